// Round 10
// baseline (959.352 us; speedup 1.0000x reference)
//
#include <hip/hip_runtime.h>
#include <hip/hip_bf16.h>
#include <stdint.h>

// BitNet MNIST MLP, Round 9: GEMM rebuilt as 4 waves (1/SIMD, 512-reg budget),
// 2x2 wave grid, acc[8][8]+full-K-tile frag residency (~360 regs, no spill),
// 1 barrier + 1 vmcnt(0) per K-tile, LDS reads 128KB/K-tile (was 192).
// Non-GEMM kernels kept verbatim from r8 (passing).

typedef __attribute__((ext_vector_type(8))) short short8;
typedef __attribute__((ext_vector_type(4))) float f32x4;

#define B_TOTAL 65536
#define IN_DIM 784
#define IN_PAD 896
#define H_DIM 1024
#define OUT_DIM 10
#define OUT_PAD 16

__device__ __forceinline__ unsigned short f2bf(float f) {
    union { float f; unsigned u; } c; c.f = f;
    unsigned r = c.u + 0x7FFFu + ((c.u >> 16) & 1u);
    return (unsigned short)(r >> 16);
}
__device__ __forceinline__ float bf2f(unsigned short h) {
    union { unsigned u; float f; } c; c.u = ((unsigned)h) << 16;
    return c.f;
}

// exact-gelu via A&S 7.1.26 erf approximation, |eps| <= 1.5e-7.
__device__ __forceinline__ float gelu_fast(float t) {
    const float z = t * 0.70710678118f;
    const float s = fabsf(z);
    const float tt = 1.0f / (1.0f + 0.3275911f * s);
    const float e = __expf(-s * s);
    float p = fmaf(tt, 1.061405429f, -1.453152027f);
    p = fmaf(tt, p, 1.421413741f);
    p = fmaf(tt, p, -0.284496736f);
    p = fmaf(tt, p, 0.254829592f);
    float erfa = fmaf(-p * tt, e, 1.0f);          // erf(|z|)
    erfa = copysignf(erfa, z);
    return 0.5f * t * (1.0f + erfa);
}

#define GLOAD16(gp, lp)                                                        \
    __builtin_amdgcn_global_load_lds(                                          \
        (const __attribute__((address_space(1))) void*)(gp),                   \
        (__attribute__((address_space(3))) void*)(lp), 16, 0, 0)

// ---------- |w| sums for all 3 weights (grid.y selects; double atomics) ----------
__global__ void absum3_kernel(const float* __restrict__ w1, const float* __restrict__ w2,
                              const float* __restrict__ w3, double* acc) {
    __shared__ float red[4];
    const int which = blockIdx.y;
    const float* w = (which == 0) ? w1 : (which == 1) ? w2 : w3;
    const int n = (which == 0) ? H_DIM * IN_DIM : (which == 1) ? H_DIM * H_DIM : OUT_DIM * H_DIM;
    float s = 0.f;
    for (int i = blockIdx.x * blockDim.x + threadIdx.x; i < n; i += gridDim.x * blockDim.x)
        s += fabsf(w[i]);
#pragma unroll
    for (int o = 32; o > 0; o >>= 1) s += __shfl_xor(s, o);
    if ((threadIdx.x & 63) == 0) red[threadIdx.x >> 6] = s;
    __syncthreads();
    if (threadIdx.x == 0) {
        float t = red[0] + red[1] + red[2] + red[3];
        atomicAdd(acc + which, (double)t);
    }
}

// ---------- ternary quantize all 3 weights -> bf16 (grid.y = flat row) ----------
__global__ void quant_all(const float* __restrict__ w1, const float* __restrict__ w2,
                          const float* __restrict__ w3,
                          unsigned short* __restrict__ w1q, unsigned short* __restrict__ w2q,
                          unsigned short* __restrict__ w3q, const double* sums) {
    const int k = blockIdx.x * blockDim.x + threadIdx.x;
    const int y = blockIdx.y;
    const float* w; unsigned short* wq; int o, O, K, Kp, n; const double* sum;
    if (y < 1024)      { w = w1; wq = w1q; o = y;        O = H_DIM;  K = IN_DIM; Kp = IN_PAD; n = H_DIM * IN_DIM;  sum = sums + 0; }
    else if (y < 2048) { w = w2; wq = w2q; o = y - 1024; O = H_DIM;  K = H_DIM;  Kp = H_DIM;  n = H_DIM * H_DIM;  sum = sums + 1; }
    else               { w = w3; wq = w3q; o = y - 2048; O = OUT_DIM; K = H_DIM; Kp = H_DIM;  n = OUT_DIM * H_DIM; sum = sums + 2; }
    if (k >= Kp) return;
    float scale = fmaxf((float)(*sum / (double)n), 1e-5f);
    float q = 0.f;
    if (o < O && k < K) {
        float r = rintf(w[(size_t)o * K + k] / scale);  // round-half-even == jnp.round
        q = fminf(1.f, fmaxf(-1.f, r));
    }
    wq[(size_t)o * Kp + k] = f2bf(q);
}

// ---------- x fp32 [R x 784] -> bf16 [R x 896] (zero-padded) ----------
__global__ __launch_bounds__(256)
void convert_pad(const float* __restrict__ x, unsigned short* __restrict__ xb) {
    const int g = blockIdx.x * 256 + threadIdx.x;   // one 8-col group per thread
    const int row = g / 112;
    const int c = (g % 112) * 8;
    short8 v = 0;
    if (c < IN_DIM) {
        const float* p = x + (size_t)row * IN_DIM + c;
        float4 f0 = *(const float4*)p;
        float4 f1 = *(const float4*)(p + 4);
        v[0] = (short)f2bf(f0.x); v[1] = (short)f2bf(f0.y);
        v[2] = (short)f2bf(f0.z); v[3] = (short)f2bf(f0.w);
        v[4] = (short)f2bf(f1.x); v[5] = (short)f2bf(f1.y);
        v[6] = (short)f2bf(f1.z); v[7] = (short)f2bf(f1.w);
    }
    *(short8*)(xb + (size_t)row * IN_PAD + c) = v;
}

// ---------- GEMM: C[M x 1024] = A[M x KP] * Bq[1024 x KP]^T ----------
// 256x256 tile, 4 waves (2m x 2n, 1 wave/SIMD, 512-reg budget), BK=64,
// 2 K-tile LDS ring (128 KB), st_16x32 swizzle. Per K-tile: one barrier,
// 32 frag ds_reads (full residency), 16 global_load_lds/thread staging the
// next tile, 128 MFMAs, vmcnt(0) (stages landed under the MFMA cluster).
// Slot st in [0,32): rows [(st>>1)*16,+16), cols [(st&1)*32,+32) of the tile.
template<int KP>
__global__ __launch_bounds__(256, 1)
void gemm_bt(const unsigned short* __restrict__ A, const unsigned short* __restrict__ Bq,
             unsigned short* __restrict__ C) {
    constexpr int NT = KP / 64;
    __shared__ __attribute__((aligned(16))) unsigned short LDS[65536];  // 128 KB
    const int tid = threadIdx.x;
    const int lane = tid & 63;
    const int w = tid >> 6;                 // 0..3
    const int wm = w >> 1, wn = w & 1;
    const int lr = lane & 15, gq = lane >> 4;
    const int gsw8 = (gq ^ ((lr >> 3) << 1)) * 8;   // swizzled granule (shorts)
    const int lrO = lr * 32;
    // XCD-grouped bijective swizzle (grid = Mblks*4, Mblks % 8 == 0)
    const int bid = blockIdx.x;
    const int xcd = bid & 7, slot = bid >> 3;
    const int nblk = slot & 3;
    const int mblk = xcd * (gridDim.x >> 5) + (slot >> 2);
    const int m0 = mblk * 256, n0 = nblk * 256;
    // staging source coords (pre-swizzled involution, verified r2-r8)
    const int rS = lane >> 2;                              // row within 16-row subtile
    const int cS = ((lane & 3) ^ ((lane >> 5) << 1)) * 8;  // swizzled col granule

// wave w stages A slots [8w,8w+8) and B slots [8w,8w+8) of the tile
#define STAGE_TILE(t, bufS)                                                    \
    _Pragma("unroll") for (int i = 0; i < 8; ++i) {                            \
        const int st = w * 8 + i;                                              \
        const int srow = (st >> 1) * 16 + rS;                                  \
        const int scol = (t) * 64 + (st & 1) * 32 + cS;                        \
        GLOAD16(A + (size_t)(m0 + srow) * KP + scol, &LDS[(bufS) + st * 512]); \
        GLOAD16(Bq + (size_t)(n0 + srow) * KP + scol,                          \
                &LDS[(bufS) + 16384 + st * 512]);                              \
    }

    f32x4 acc[8][8] = {};
    short8 af[8][2], bf[8][2];
    STAGE_TILE(0, 0);
    asm volatile("s_waitcnt vmcnt(0)" ::: "memory");
    __builtin_amdgcn_s_barrier();
#pragma unroll 2
    for (int t = 0; t < NT; ++t) {
        const int bufS = (t & 1) * 32768;
        const int nxtS = bufS ^ 32768;
        // frag reads: kk0 first so MFMA kk0 can start while kk1 reads land
#pragma unroll
        for (int mf = 0; mf < 8; ++mf)
            af[mf][0] = *(const short8*)&LDS[bufS + ((wm * 8 + mf) * 2 + 0) * 512 + lrO + gsw8];
#pragma unroll
        for (int nf = 0; nf < 8; ++nf)
            bf[nf][0] = *(const short8*)&LDS[bufS + 16384 + ((wn * 8 + nf) * 2 + 0) * 512 + lrO + gsw8];
#pragma unroll
        for (int mf = 0; mf < 8; ++mf)
            af[mf][1] = *(const short8*)&LDS[bufS + ((wm * 8 + mf) * 2 + 1) * 512 + lrO + gsw8];
#pragma unroll
        for (int nf = 0; nf < 8; ++nf)
            bf[nf][1] = *(const short8*)&LDS[bufS + 16384 + ((wn * 8 + nf) * 2 + 1) * 512 + lrO + gsw8];
        if (t + 1 < NT) STAGE_TILE(t + 1, nxtS);
        __builtin_amdgcn_s_setprio(1);
#pragma unroll
        for (int kk = 0; kk < 2; ++kk)
#pragma unroll
            for (int mf = 0; mf < 8; ++mf)
#pragma unroll
                for (int nf = 0; nf < 8; ++nf)
                    acc[mf][nf] = __builtin_amdgcn_mfma_f32_16x16x32_bf16(
                        af[mf][kk], bf[nf][kk], acc[mf][nf], 0, 0, 0);
        __builtin_amdgcn_s_setprio(0);
        asm volatile("s_waitcnt vmcnt(0)" ::: "memory");  // next tile landed
        __builtin_amdgcn_s_barrier();
    }
    // epilogue: C/D layout col=lane&15, row=(lane>>4)*4+j (HW-verified)
#pragma unroll
    for (int mf = 0; mf < 8; ++mf) {
        const int grow = m0 + wm * 128 + mf * 16 + (lane >> 4) * 4;
#pragma unroll
        for (int nf = 0; nf < 8; ++nf) {
            const int gcol = n0 + wn * 128 + nf * 16 + lr;
            unsigned short* Cp = C + (size_t)grow * H_DIM + gcol;
#pragma unroll
            for (int j = 0; j < 4; ++j) Cp[(size_t)j * H_DIM] = f2bf(acc[mf][nf][j]);
        }
    }
#undef STAGE_TILE
}

// ---------- rmsnorm + gelu (layer 1), one wave per 1024-wide row ----------
__global__ __launch_bounds__(256)
void norm_gelu(const unsigned short* __restrict__ Hp, const float* __restrict__ g,
               unsigned short* __restrict__ U) {
    const int row = blockIdx.x * 4 + (threadIdx.x >> 6);
    const int lane = threadIdx.x & 63;
    const unsigned short* rp = Hp + (size_t)row * H_DIM;
    short8 v0 = *(const short8*)(rp + lane * 8);
    short8 v1 = *(const short8*)(rp + 512 + lane * 8);
    float f[16];
#pragma unroll
    for (int j = 0; j < 8; ++j) {
        f[j] = bf2f((unsigned short)v0[j]);
        f[8 + j] = bf2f((unsigned short)v1[j]);
    }
    float s = 0.f;
#pragma unroll
    for (int j = 0; j < 16; ++j) s += f[j] * f[j];
#pragma unroll
    for (int o = 32; o > 0; o >>= 1) s += __shfl_xor(s, o);
    const float rinv = 1.f / sqrtf(s * (1.f / 1024.f) + 1e-6f);
    float4 ga0 = *(const float4*)(g + lane * 8);
    float4 ga1 = *(const float4*)(g + lane * 8 + 4);
    float4 gb0 = *(const float4*)(g + 512 + lane * 8);
    float4 gb1 = *(const float4*)(g + 512 + lane * 8 + 4);
    float gv[16] = {ga0.x, ga0.y, ga0.z, ga0.w, ga1.x, ga1.y, ga1.z, ga1.w,
                    gb0.x, gb0.y, gb0.z, gb0.w, gb1.x, gb1.y, gb1.z, gb1.w};
    short8 o0, o1;
#pragma unroll
    for (int j = 0; j < 8; ++j) {
        o0[j] = (short)f2bf(gelu_fast(f[j] * rinv * gv[j]));
        o1[j] = (short)f2bf(gelu_fast(f[8 + j] * rinv * gv[8 + j]));
    }
    unsigned short* up = U + (size_t)row * H_DIM;
    *(short8*)(up + lane * 8) = o0;
    *(short8*)(up + 512 + lane * 8) = o1;
}

// ---------- fused: rmsnorm + gelu + final 1024->10 GEMM ----------
__global__ __launch_bounds__(256)
void norm_gelu_out(const unsigned short* __restrict__ Hp, const float* __restrict__ g,
                   const unsigned short* __restrict__ w3q, float* __restrict__ out) {
    __shared__ unsigned short Us[16][1032];
    __shared__ unsigned short Ws[16][1032];
    const int tid = threadIdx.x;
    const int lane = tid & 63, wid = tid >> 6;
    const size_t r0 = (size_t)blockIdx.x * 16;
    for (int i = tid; i < 2048; i += 256) {           // stage w3: 16 x 128 granules
        const int r = i >> 7, cg = i & 127;
        *(short8*)&Ws[r][cg * 8] = *(const short8*)(w3q + (size_t)r * H_DIM + cg * 8);
    }
    float4 ga0 = *(const float4*)(g + lane * 8);
    float4 ga1 = *(const float4*)(g + lane * 8 + 4);
    float4 gb0 = *(const float4*)(g + 512 + lane * 8);
    float4 gb1 = *(const float4*)(g + 512 + lane * 8 + 4);
    float gv[16] = {ga0.x, ga0.y, ga0.z, ga0.w, ga1.x, ga1.y, ga1.z, ga1.w,
                    gb0.x, gb0.y, gb0.z, gb0.w, gb1.x, gb1.y, gb1.z, gb1.w};
#pragma unroll
    for (int rr = 0; rr < 4; ++rr) {
        const int row = wid * 4 + rr;
        const unsigned short* rp = Hp + (r0 + row) * H_DIM;
        short8 v0 = *(const short8*)(rp + lane * 8);
        short8 v1 = *(const short8*)(rp + 512 + lane * 8);
        float f[16];
#pragma unroll
        for (int j = 0; j < 8; ++j) {
            f[j] = bf2f((unsigned short)v0[j]);
            f[8 + j] = bf2f((unsigned short)v1[j]);
        }
        float s = 0.f;
#pragma unroll
        for (int j = 0; j < 16; ++j) s += f[j] * f[j];
#pragma unroll
        for (int o = 32; o > 0; o >>= 1) s += __shfl_xor(s, o);
        const float rinv = 1.f / sqrtf(s * (1.f / 1024.f) + 1e-6f);
        short8 o0, o1;
#pragma unroll
        for (int j = 0; j < 8; ++j) {
            o0[j] = (short)f2bf(gelu_fast(f[j] * rinv * gv[j]));
            o1[j] = (short)f2bf(gelu_fast(f[8 + j] * rinv * gv[8 + j]));
        }
        *(short8*)&Us[row][lane * 8] = o0;
        *(short8*)&Us[row][512 + lane * 8] = o1;
    }
    __syncthreads();
    if (wid == 0) {
        const int lr = lane & 15, lk = (lane >> 4) * 8;
        f32x4 acc = {};
#pragma unroll
        for (int ks = 0; ks < 32; ++ks) {
            short8 a = *(const short8*)&Us[lr][ks * 32 + lk];
            short8 b = *(const short8*)&Ws[lr][ks * 32 + lk];
            acc = __builtin_amdgcn_mfma_f32_16x16x32_bf16(a, b, acc, 0, 0, 0);
        }
        if (lr < OUT_DIM) {
#pragma unroll
            for (int j = 0; j < 4; ++j)
                out[(r0 + (lane >> 4) * 4 + j) * OUT_DIM + lr] = acc[j];
        }
    }
}

extern "C" void kernel_launch(void* const* d_in, const int* in_sizes, int n_in,
                              void* d_out, int out_size, void* d_ws, size_t ws_size,
                              hipStream_t stream) {
    (void)in_sizes; (void)n_in; (void)out_size;
    const float* x  = (const float*)d_in[0];
    const float* w1 = (const float*)d_in[1];
    const float* g1 = (const float*)d_in[2];
    const float* w2 = (const float*)d_in[3];
    const float* g2 = (const float*)d_in[4];
    const float* w3 = (const float*)d_in[5];
    float* out = (float*)d_out;

    uint8_t* ws = (uint8_t*)d_ws;
    double* sums = (double*)ws;
    size_t off = 256;
    unsigned short* w1q = (unsigned short*)(ws + off); off += (size_t)H_DIM * IN_PAD * 2;
    unsigned short* w2q = (unsigned short*)(ws + off); off += (size_t)H_DIM * H_DIM * 2;
    unsigned short* w3q = (unsigned short*)(ws + off); off += (size_t)OUT_PAD * H_DIM * 2;

    size_t rem = (ws_size > off) ? ws_size - off : 0;
    int R = B_TOTAL;
    while (R > 2048 && (size_t)2 * R * H_DIM * 2 > rem) R >>= 1;
    unsigned short* bufA = (unsigned short*)(ws + off);
    unsigned short* bufB = bufA + (size_t)R * H_DIM;

    hipMemsetAsync(sums, 0, 3 * sizeof(double), stream);
    absum3_kernel<<<dim3(128, 3), 256, 0, stream>>>(w1, w2, w3, sums);
    quant_all<<<dim3(4, 2064), 256, 0, stream>>>(w1, w2, w3, w1q, w2q, w3q, sums);

    const int nchunk = B_TOTAL / R;
    for (int c = 0; c < nchunk; ++c) {
        const float* xc = x + (size_t)c * R * IN_DIM;
        convert_pad<<<R * 112 / 256, 256, 0, stream>>>(xc, bufB);
        gemm_bt<IN_PAD><<<(R / 256) * 4, 256, 0, stream>>>(bufB, w1q, bufA);
        norm_gelu<<<R / 4, 256, 0, stream>>>(bufA, g1, bufB);
        gemm_bt<H_DIM><<<(R / 256) * 4, 256, 0, stream>>>(bufB, w2q, bufA);
        norm_gelu_out<<<R / 16, 256, 0, stream>>>(bufA, g2, w3q, out + (size_t)c * R * OUT_DIM);
    }
}

// Round 11
// 447.969 us; speedup vs baseline: 2.1416x; 2.1416x over previous
//
#include <hip/hip_runtime.h>
#include <hip/hip_bf16.h>
#include <stdint.h>

// BitNet MNIST MLP, Round 10: r9's fat-wave GEMM spilled (VGPR cap 256) -> reverted.
// gemm2 = r8-exact 8-wave structure (known 149us). gemm1 = A/B test of the
// m201-faithful variant: reads+stage BEFORE barrier, s_barrier -> lgkmcnt(0) ->
// setprio MFMA -> s_barrier, NO sched_barrier pins (the one untested cell:
// r2/r4 had pins at 37%, r6 had reads-after-barrier at 38%).
// IN_PAD 896 -> 832 (13 K-tiles, still >= 784).

typedef __attribute__((ext_vector_type(8))) short short8;
typedef __attribute__((ext_vector_type(4))) float f32x4;

#define B_TOTAL 65536
#define IN_DIM 784
#define IN_PAD 832
#define H_DIM 1024
#define OUT_DIM 10
#define OUT_PAD 16

__device__ __forceinline__ unsigned short f2bf(float f) {
    union { float f; unsigned u; } c; c.f = f;
    unsigned r = c.u + 0x7FFFu + ((c.u >> 16) & 1u);
    return (unsigned short)(r >> 16);
}
__device__ __forceinline__ float bf2f(unsigned short h) {
    union { unsigned u; float f; } c; c.u = ((unsigned)h) << 16;
    return c.f;
}

// exact-gelu via A&S 7.1.26 erf approximation, |eps| <= 1.5e-7.
__device__ __forceinline__ float gelu_fast(float t) {
    const float z = t * 0.70710678118f;
    const float s = fabsf(z);
    const float tt = 1.0f / (1.0f + 0.3275911f * s);
    const float e = __expf(-s * s);
    float p = fmaf(tt, 1.061405429f, -1.453152027f);
    p = fmaf(tt, p, 1.421413741f);
    p = fmaf(tt, p, -0.284496736f);
    p = fmaf(tt, p, 0.254829592f);
    float erfa = fmaf(-p * tt, e, 1.0f);          // erf(|z|)
    erfa = copysignf(erfa, z);
    return 0.5f * t * (1.0f + erfa);
}

#define GLOAD16(gp, lp)                                                        \
    __builtin_amdgcn_global_load_lds(                                          \
        (const __attribute__((address_space(1))) void*)(gp),                   \
        (__attribute__((address_space(3))) void*)(lp), 16, 0, 0)

// ---------- |w| sums for all 3 weights (grid.y selects; double atomics) ----------
__global__ void absum3_kernel(const float* __restrict__ w1, const float* __restrict__ w2,
                              const float* __restrict__ w3, double* acc) {
    __shared__ float red[4];
    const int which = blockIdx.y;
    const float* w = (which == 0) ? w1 : (which == 1) ? w2 : w3;
    const int n = (which == 0) ? H_DIM * IN_DIM : (which == 1) ? H_DIM * H_DIM : OUT_DIM * H_DIM;
    float s = 0.f;
    for (int i = blockIdx.x * blockDim.x + threadIdx.x; i < n; i += gridDim.x * blockDim.x)
        s += fabsf(w[i]);
#pragma unroll
    for (int o = 32; o > 0; o >>= 1) s += __shfl_xor(s, o);
    if ((threadIdx.x & 63) == 0) red[threadIdx.x >> 6] = s;
    __syncthreads();
    if (threadIdx.x == 0) {
        float t = red[0] + red[1] + red[2] + red[3];
        atomicAdd(acc + which, (double)t);
    }
}

// ---------- ternary quantize all 3 weights -> bf16 (grid.y = flat row) ----------
__global__ void quant_all(const float* __restrict__ w1, const float* __restrict__ w2,
                          const float* __restrict__ w3,
                          unsigned short* __restrict__ w1q, unsigned short* __restrict__ w2q,
                          unsigned short* __restrict__ w3q, const double* sums) {
    const int k = blockIdx.x * blockDim.x + threadIdx.x;
    const int y = blockIdx.y;
    const float* w; unsigned short* wq; int o, O, K, Kp, n; const double* sum;
    if (y < 1024)      { w = w1; wq = w1q; o = y;        O = H_DIM;  K = IN_DIM; Kp = IN_PAD; n = H_DIM * IN_DIM;  sum = sums + 0; }
    else if (y < 2048) { w = w2; wq = w2q; o = y - 1024; O = H_DIM;  K = H_DIM;  Kp = H_DIM;  n = H_DIM * H_DIM;  sum = sums + 1; }
    else               { w = w3; wq = w3q; o = y - 2048; O = OUT_DIM; K = H_DIM; Kp = H_DIM;  n = OUT_DIM * H_DIM; sum = sums + 2; }
    if (k >= Kp) return;
    float scale = fmaxf((float)(*sum / (double)n), 1e-5f);
    float q = 0.f;
    if (o < O && k < K) {
        float r = rintf(w[(size_t)o * K + k] / scale);  // round-half-even == jnp.round
        q = fminf(1.f, fmaxf(-1.f, r));
    }
    wq[(size_t)o * Kp + k] = f2bf(q);
}

// ---------- x fp32 [R x 784] -> bf16 [R x 832] (zero-padded) ----------
__global__ __launch_bounds__(256)
void convert_pad(const float* __restrict__ x, unsigned short* __restrict__ xb) {
    const int g = blockIdx.x * 256 + threadIdx.x;   // one 8-col group per thread
    const int row = g / 104;
    const int c = (g % 104) * 8;
    short8 v = 0;
    if (c < IN_DIM) {
        const float* p = x + (size_t)row * IN_DIM + c;
        float4 f0 = *(const float4*)p;
        float4 f1 = *(const float4*)(p + 4);
        v[0] = (short)f2bf(f0.x); v[1] = (short)f2bf(f0.y);
        v[2] = (short)f2bf(f0.z); v[3] = (short)f2bf(f0.w);
        v[4] = (short)f2bf(f1.x); v[5] = (short)f2bf(f1.y);
        v[6] = (short)f2bf(f1.z); v[7] = (short)f2bf(f1.w);
    }
    *(short8*)(xb + (size_t)row * IN_PAD + c) = v;
}

// ================= shared GEMM geometry helpers (macros) =================
#define GEMM_PREAMBLE(KP)                                                      \
    constexpr int NT = (KP) / 64;                                              \
    __shared__ __attribute__((aligned(16))) unsigned short LDS[65536];         \
    const int tid = threadIdx.x;                                               \
    const int lane = tid & 63;                                                 \
    const int w = tid >> 6;                                                    \
    const int wm = w >> 2, wn = w & 3;                                         \
    const int lr = lane & 15, gq = lane >> 4;                                  \
    const int gsw8 = (gq ^ ((lr >> 3) << 1)) * 8;                              \
    const int lrO = lr * 32;                                                   \
    const int bid = blockIdx.x;                                                \
    const int xcd = bid & 7, slot = bid >> 3;                                  \
    const int nblk = slot & 3;                                                 \
    const int mblk = xcd * (gridDim.x >> 5) + (slot >> 2);                     \
    const int m0 = mblk * 256, n0 = nblk * 256;                                \
    const int rS = lane >> 2;                                                  \
    const int cS = ((lane & 3) ^ ((lane >> 5) << 1)) * 8;                      \
    const int stA0 = w;                                                        \
    const int stA1 = 8 + w;                                                    \
    const int stB_P1 = (w >> 2) * 8 + (w & 3);                                 \
    const int stB_P3 = stB_P1 + 4;

#define STG(KP, gbase, areaS, st)                                              \
    {   const unsigned short* _g = (gbase) +                                   \
            (size_t)(((st) >> 1) * 16 + rS) * (KP) + ((st) & 1) * 32 + cS;     \
        GLOAD16(_g, &LDS[(areaS) + (st) * 512]);                               \
        GLOAD16(_g + (size_t)128 * (KP), &LDS[(areaS) + (st) * 512 + 8192]); }
#define LD_A(mq)                                                               \
    _Pragma("unroll") for (int mf = 0; mf < 4; ++mf)                           \
    _Pragma("unroll") for (int kk = 0; kk < 2; ++kk)                           \
        af[mf][kk] = *(const short8*)&LDS[curS +                               \
            ((wm * 8 + (mq) * 4 + mf) * 2 + kk) * 512 + lrO + gsw8];
#define LD_B(nq)                                                               \
    _Pragma("unroll") for (int nf = 0; nf < 2; ++nf)                           \
    _Pragma("unroll") for (int kk = 0; kk < 2; ++kk)                           \
        bf[nf][kk] = *(const short8*)&LDS[curS + 16384 +                       \
            ((wn * 4 + (nq) * 2 + nf) * 2 + kk) * 512 + lrO + gsw8];
#define QMM(mq, nq)                                                            \
    _Pragma("unroll") for (int kk = 0; kk < 2; ++kk)                           \
    _Pragma("unroll") for (int mf = 0; mf < 4; ++mf)                           \
    _Pragma("unroll") for (int nf = 0; nf < 2; ++nf)                           \
        acc[(mq) * 4 + mf][(nq) * 2 + nf] =                                    \
            __builtin_amdgcn_mfma_f32_16x16x32_bf16(af[mf][kk], bf[nf][kk],    \
                acc[(mq) * 4 + mf][(nq) * 2 + nf], 0, 0, 0);
#define GEMM_PROLOGUE(KP)                                                      \
    STG(KP, A + (size_t)m0 * (KP), 0, stA0);                                   \
    STG(KP, Bq + (size_t)n0 * (KP), 16384, stB_P1);                            \
    STG(KP, Bq + (size_t)n0 * (KP), 16384, stB_P3);                            \
    STG(KP, A + (size_t)m0 * (KP), 0, stA1);                                   \
    STG(KP, A + (size_t)m0 * (KP) + 64, 32768, stA0);                          \
    STG(KP, Bq + (size_t)n0 * (KP) + 64, 49152, stB_P3);                       \
    STG(KP, A + (size_t)m0 * (KP) + 64, 32768, stA1);                          \
    asm volatile("s_waitcnt vmcnt(6)" ::: "memory");
#define GEMM_EPILOGUE()                                                        \
    _Pragma("unroll") for (int mf = 0; mf < 8; ++mf) {                         \
        const int grow = m0 + wm * 128 + mf * 16 + (lane >> 4) * 4;            \
        _Pragma("unroll") for (int nf = 0; nf < 4; ++nf) {                     \
            const int gcol = n0 + wn * 64 + nf * 16 + lr;                      \
            unsigned short* Cp = C + (size_t)grow * H_DIM + gcol;              \
            _Pragma("unroll") for (int j = 0; j < 4; ++j)                      \
                Cp[(size_t)j * H_DIM] = f2bf(acc[mf][nf][j]);                  \
        }                                                                      \
    }

// ---------- GEMM (r8-exact structure): reads AFTER barrier, 4 bar/K-tile ----------
template<int KP>
__global__ __launch_bounds__(512, 2)
void gemm_bt(const unsigned short* __restrict__ A, const unsigned short* __restrict__ Bq,
             unsigned short* __restrict__ C) {
    GEMM_PREAMBLE(KP)
    f32x4 acc[8][4] = {};
    short8 af[4][2], bf[2][2];
    GEMM_PROLOGUE(KP)
#pragma unroll 2
    for (int t = 0; t < NT; ++t) {
        const int curS = (t & 1) * 32768;
        const int nxtS = curS ^ 32768;
        __builtin_amdgcn_s_barrier();
        LD_A(0); LD_B(0);
        __builtin_amdgcn_s_setprio(1); QMM(0, 0); __builtin_amdgcn_s_setprio(0);
        if (t + 1 < NT) STG(KP, Bq + (size_t)n0 * KP + (t + 1) * 64, nxtS + 16384, stB_P1);
        __builtin_amdgcn_s_barrier();
        LD_B(1);
        __builtin_amdgcn_s_setprio(1); QMM(0, 1); __builtin_amdgcn_s_setprio(0);
        if (t + 2 < NT) STG(KP, A + (size_t)m0 * KP + (t + 2) * 64, curS, stA0);
        __builtin_amdgcn_s_barrier();
        LD_A(1);
        __builtin_amdgcn_s_setprio(1); QMM(1, 1); __builtin_amdgcn_s_setprio(0);
        if (t + 2 < NT) STG(KP, Bq + (size_t)n0 * KP + (t + 2) * 64, curS + 16384, stB_P3);
        __builtin_amdgcn_s_barrier();
        LD_B(0);
        __builtin_amdgcn_s_setprio(1); QMM(1, 0); __builtin_amdgcn_s_setprio(0);
        if (t + 2 < NT) STG(KP, A + (size_t)m0 * KP + (t + 2) * 64, curS, stA1);
        if (t < NT - 2) { asm volatile("s_waitcnt vmcnt(6)" ::: "memory"); }
        else            { asm volatile("s_waitcnt vmcnt(0)" ::: "memory"); }
    }
    GEMM_EPILOGUE()
}

// ---------- GEMM v2 (m201-faithful): reads+stage BEFORE barrier, then
// s_barrier -> lgkmcnt(0) -> setprio MFMA -> s_barrier; no sched pins.
// Same slot lifetimes / vmcnt ledger as the verified r4 schedule. ----------
template<int KP>
__global__ __launch_bounds__(512, 2)
void gemm_bt_v2(const unsigned short* __restrict__ A, const unsigned short* __restrict__ Bq,
                unsigned short* __restrict__ C) {
    GEMM_PREAMBLE(KP)
    f32x4 acc[8][4] = {};
    short8 af[4][2], bf[2][2];
    GEMM_PROLOGUE(KP)
    __builtin_amdgcn_s_barrier();
#pragma unroll 2
    for (int t = 0; t < NT; ++t) {
        const int curS = (t & 1) * 32768;
        const int nxtS = curS ^ 32768;
        // P1: Q(0,0); stage B-nq0(t+1)->nxt (last read P4(t-1), drained pre-barrier)
        LD_A(0); LD_B(0);
        if (t + 1 < NT) STG(KP, Bq + (size_t)n0 * KP + (t + 1) * 64, nxtS + 16384, stB_P1);
        __builtin_amdgcn_s_barrier();
        asm volatile("s_waitcnt lgkmcnt(0)" ::: "memory");
        __builtin_amdgcn_s_setprio(1); QMM(0, 0); __builtin_amdgcn_s_setprio(0);
        __builtin_amdgcn_s_barrier();
        // P2: Q(0,1); stage A-g0(t+2)->cur (A-g0(t) read drained before P1 QMM)
        LD_B(1);
        if (t + 2 < NT) STG(KP, A + (size_t)m0 * KP + (t + 2) * 64, curS, stA0);
        __builtin_amdgcn_s_barrier();
        asm volatile("s_waitcnt lgkmcnt(0)" ::: "memory");
        __builtin_amdgcn_s_setprio(1); QMM(0, 1); __builtin_amdgcn_s_setprio(0);
        __builtin_amdgcn_s_barrier();
        // P3: Q(1,1); stage B-nq1(t+2)->cur (read drained before P2 QMM)
        LD_A(1);
        if (t + 2 < NT) STG(KP, Bq + (size_t)n0 * KP + (t + 2) * 64, curS + 16384, stB_P3);
        __builtin_amdgcn_s_barrier();
        asm volatile("s_waitcnt lgkmcnt(0)" ::: "memory");
        __builtin_amdgcn_s_setprio(1); QMM(1, 1); __builtin_amdgcn_s_setprio(0);
        __builtin_amdgcn_s_barrier();
        // P4: Q(1,0); stage A-g1(t+2)->cur (read drained before P3 QMM)
        LD_B(0);
        if (t + 2 < NT) STG(KP, A + (size_t)m0 * KP + (t + 2) * 64, curS, stA1);
        __builtin_amdgcn_s_barrier();
        asm volatile("s_waitcnt lgkmcnt(0)" ::: "memory");
        __builtin_amdgcn_s_setprio(1); QMM(1, 0); __builtin_amdgcn_s_setprio(0);
        // fence: tile t+1 fully landed; tile t+2's 3 groups stay in flight
        if (t < NT - 2) { asm volatile("s_waitcnt vmcnt(6)" ::: "memory"); }
        else            { asm volatile("s_waitcnt vmcnt(0)" ::: "memory"); }
        __builtin_amdgcn_s_barrier();
    }
    GEMM_EPILOGUE()
}

// ---------- rmsnorm + gelu (layer 1), one wave per 1024-wide row ----------
__global__ __launch_bounds__(256)
void norm_gelu(const unsigned short* __restrict__ Hp, const float* __restrict__ g,
               unsigned short* __restrict__ U) {
    const int row = blockIdx.x * 4 + (threadIdx.x >> 6);
    const int lane = threadIdx.x & 63;
    const unsigned short* rp = Hp + (size_t)row * H_DIM;
    short8 v0 = *(const short8*)(rp + lane * 8);
    short8 v1 = *(const short8*)(rp + 512 + lane * 8);
    float f[16];
#pragma unroll
    for (int j = 0; j < 8; ++j) {
        f[j] = bf2f((unsigned short)v0[j]);
        f[8 + j] = bf2f((unsigned short)v1[j]);
    }
    float s = 0.f;
#pragma unroll
    for (int j = 0; j < 16; ++j) s += f[j] * f[j];
#pragma unroll
    for (int o = 32; o > 0; o >>= 1) s += __shfl_xor(s, o);
    const float rinv = 1.f / sqrtf(s * (1.f / 1024.f) + 1e-6f);
    float4 ga0 = *(const float4*)(g + lane * 8);
    float4 ga1 = *(const float4*)(g + lane * 8 + 4);
    float4 gb0 = *(const float4*)(g + 512 + lane * 8);
    float4 gb1 = *(const float4*)(g + 512 + lane * 8 + 4);
    float gv[16] = {ga0.x, ga0.y, ga0.z, ga0.w, ga1.x, ga1.y, ga1.z, ga1.w,
                    gb0.x, gb0.y, gb0.z, gb0.w, gb1.x, gb1.y, gb1.z, gb1.w};
    short8 o0, o1;
#pragma unroll
    for (int j = 0; j < 8; ++j) {
        o0[j] = (short)f2bf(gelu_fast(f[j] * rinv * gv[j]));
        o1[j] = (short)f2bf(gelu_fast(f[8 + j] * rinv * gv[8 + j]));
    }
    unsigned short* up = U + (size_t)row * H_DIM;
    *(short8*)(up + lane * 8) = o0;
    *(short8*)(up + 512 + lane * 8) = o1;
}

// ---------- fused: rmsnorm + gelu + final 1024->10 GEMM ----------
__global__ __launch_bounds__(256)
void norm_gelu_out(const unsigned short* __restrict__ Hp, const float* __restrict__ g,
                   const unsigned short* __restrict__ w3q, float* __restrict__ out) {
    __shared__ unsigned short Us[16][1032];
    __shared__ unsigned short Ws[16][1032];
    const int tid = threadIdx.x;
    const int lane = tid & 63, wid = tid >> 6;
    const size_t r0 = (size_t)blockIdx.x * 16;
    for (int i = tid; i < 2048; i += 256) {           // stage w3: 16 x 128 granules
        const int r = i >> 7, cg = i & 127;
        *(short8*)&Ws[r][cg * 8] = *(const short8*)(w3q + (size_t)r * H_DIM + cg * 8);
    }
    float4 ga0 = *(const float4*)(g + lane * 8);
    float4 ga1 = *(const float4*)(g + lane * 8 + 4);
    float4 gb0 = *(const float4*)(g + 512 + lane * 8);
    float4 gb1 = *(const float4*)(g + 512 + lane * 8 + 4);
    float gv[16] = {ga0.x, ga0.y, ga0.z, ga0.w, ga1.x, ga1.y, ga1.z, ga1.w,
                    gb0.x, gb0.y, gb0.z, gb0.w, gb1.x, gb1.y, gb1.z, gb1.w};
#pragma unroll
    for (int rr = 0; rr < 4; ++rr) {
        const int row = wid * 4 + rr;
        const unsigned short* rp = Hp + (r0 + row) * H_DIM;
        short8 v0 = *(const short8*)(rp + lane * 8);
        short8 v1 = *(const short8*)(rp + 512 + lane * 8);
        float f[16];
#pragma unroll
        for (int j = 0; j < 8; ++j) {
            f[j] = bf2f((unsigned short)v0[j]);
            f[8 + j] = bf2f((unsigned short)v1[j]);
        }
        float s = 0.f;
#pragma unroll
        for (int j = 0; j < 16; ++j) s += f[j] * f[j];
#pragma unroll
        for (int o = 32; o > 0; o >>= 1) s += __shfl_xor(s, o);
        const float rinv = 1.f / sqrtf(s * (1.f / 1024.f) + 1e-6f);
        short8 o0, o1;
#pragma unroll
        for (int j = 0; j < 8; ++j) {
            o0[j] = (short)f2bf(gelu_fast(f[j] * rinv * gv[j]));
            o1[j] = (short)f2bf(gelu_fast(f[8 + j] * rinv * gv[8 + j]));
        }
        *(short8*)&Us[row][lane * 8] = o0;
        *(short8*)&Us[row][512 + lane * 8] = o1;
    }
    __syncthreads();
    if (wid == 0) {
        const int lr = lane & 15, lk = (lane >> 4) * 8;
        f32x4 acc = {};
#pragma unroll
        for (int ks = 0; ks < 32; ++ks) {
            short8 a = *(const short8*)&Us[lr][ks * 32 + lk];
            short8 b = *(const short8*)&Ws[lr][ks * 32 + lk];
            acc = __builtin_amdgcn_mfma_f32_16x16x32_bf16(a, b, acc, 0, 0, 0);
        }
        if (lr < OUT_DIM) {
#pragma unroll
            for (int j = 0; j < 4; ++j)
                out[(r0 + (lane >> 4) * 4 + j) * OUT_DIM + lr] = acc[j];
        }
    }
}

extern "C" void kernel_launch(void* const* d_in, const int* in_sizes, int n_in,
                              void* d_out, int out_size, void* d_ws, size_t ws_size,
                              hipStream_t stream) {
    (void)in_sizes; (void)n_in; (void)out_size;
    const float* x  = (const float*)d_in[0];
    const float* w1 = (const float*)d_in[1];
    const float* g1 = (const float*)d_in[2];
    const float* w2 = (const float*)d_in[3];
    const float* g2 = (const float*)d_in[4];
    const float* w3 = (const float*)d_in[5];
    float* out = (float*)d_out;

    uint8_t* ws = (uint8_t*)d_ws;
    double* sums = (double*)ws;
    size_t off = 256;
    unsigned short* w1q = (unsigned short*)(ws + off); off += (size_t)H_DIM * IN_PAD * 2;
    unsigned short* w2q = (unsigned short*)(ws + off); off += (size_t)H_DIM * H_DIM * 2;
    unsigned short* w3q = (unsigned short*)(ws + off); off += (size_t)OUT_PAD * H_DIM * 2;

    size_t rem = (ws_size > off) ? ws_size - off : 0;
    int R = B_TOTAL;
    while (R > 2048 && (size_t)2 * R * H_DIM * 2 > rem) R >>= 1;
    unsigned short* bufA = (unsigned short*)(ws + off);
    unsigned short* bufB = bufA + (size_t)R * H_DIM;

    hipMemsetAsync(sums, 0, 3 * sizeof(double), stream);
    absum3_kernel<<<dim3(128, 3), 256, 0, stream>>>(w1, w2, w3, sums);
    quant_all<<<dim3(4, 2064), 256, 0, stream>>>(w1, w2, w3, w1q, w2q, w3q, sums);

    const int nchunk = B_TOTAL / R;
    for (int c = 0; c < nchunk; ++c) {
        const float* xc = x + (size_t)c * R * IN_DIM;
        convert_pad<<<R * 104 / 256, 256, 0, stream>>>(xc, bufB);
        gemm_bt_v2<IN_PAD><<<(R / 256) * 4, 512, 0, stream>>>(bufB, w1q, bufA);
        norm_gelu<<<R / 4, 256, 0, stream>>>(bufA, g1, bufB);
        gemm_bt<H_DIM><<<(R / 256) * 4, 512, 0, stream>>>(bufB, w2q, bufA);
        norm_gelu_out<<<R / 16, 256, 0, stream>>>(bufA, g2, w3q, out + (size_t)c * R * OUT_DIM);
    }
}